// Round 6
// baseline (84.335 us; speedup 1.0000x reference)
//
#include <hip/hip_runtime.h>
#include <math.h>

#define B_    4
#define TDEC  512
#define TENC  1024
#define H_    128
#define DT    4

// tanh(enc) repacked: [b][g:32][e:1024][j:4]  (thread reads one dwordx4 per g)
__device__ float g_tetp[(size_t)B_ * 32 * TENC * 4];           // 2 MB
// per (row-tile, g) broadcast pack: [v4(4) td_d0..d3(16) vt_d0..d3(16)] = 36 f
__device__ float g_tdvt[(size_t)B_ * 128 * 32 * 36];           // 2.25 MB
__device__ float g_scr[(size_t)B_ * TDEC * TENC];              // 8 MB raw scores

struct TDVG { float4 v4, td0, td1, td2, td3, vt0, vt1, vt2, vt3; };

union F4 { float4 v; float f[4]; };

__device__ __forceinline__ float ftanh(float x) {
    float e = __expf(2.f * x);
    return fmaf(-2.f, __builtin_amdgcn_rcpf(e + 1.f), 1.f);
}

// z<4: transpose+tanh enc -> g_tetp (float4 per (g,e)).   z==4: TD rows + tdvt pack.
__global__ __launch_bounds__(256) void prep_kernel(const float* __restrict__ enc,
                                                   const float* __restrict__ dec,
                                                   const float* __restrict__ Ww,
                                                   const float* __restrict__ Wb,
                                                   const float* __restrict__ Vw) {
    const int z = blockIdx.z;
    const int tx = threadIdx.x, ty = threadIdx.y;
    if (z < B_) {
        __shared__ float tile[32][33];               // [e-local][h-local]
        const int e0 = blockIdx.x * 32, h0 = blockIdx.y * 32, b = z;
        const float* ep = enc + (size_t)b * TENC * H_;
        #pragma unroll
        for (int j = 0; j < 32; j += 8)
            tile[ty + j][tx] = ep[(size_t)(e0 + ty + j) * H_ + h0 + tx];
        __syncthreads();
        // thread (tx,ty): e = e0+tx, g = h0/4 + ty, j = 0..3  -> float4 store
        const int g = (h0 >> 2) + ty, e = e0 + tx;
        float4 o;
        o.x = ftanh(tile[tx][4 * ty + 0]);
        o.y = ftanh(tile[tx][4 * ty + 1]);
        o.z = ftanh(tile[tx][4 * ty + 2]);
        o.w = ftanh(tile[tx][4 * ty + 3]);
        *(float4*)&g_tetp[(((size_t)b * 32 + g) * TENC + e) * 4] = o;
        // second set of g's (ty covers 8, need 8 g per 32-h tile: exactly 8) done.
    } else {
        // 128 blocks x 16 rows: td = tanh(dec @ Ww^T + Wb); pack td & v*td
        __shared__ float ds[16][H_];
        const int t = ty * 32 + tx;
        const int blk = blockIdx.y * 32 + blockIdx.x;      // 0..127
        const int R0 = blk * 16;
        #pragma unroll
        for (int i = 0; i < 8; ++i) {
            const int f = t + 256 * i;
            ds[f >> 7][f & 127] = dec[(size_t)R0 * H_ + f];
        }
        __syncthreads();
        const int k = t & 127, dd = t >> 7;
        const float* wr = Ww + (size_t)k * H_;
        float s[8];
        #pragma unroll
        for (int j = 0; j < 8; ++j) s[j] = 0.f;
        for (int h = 0; h < H_; h += 4) {
            const float4 w4 = *(const float4*)(wr + h);
            #pragma unroll
            for (int j = 0; j < 8; ++j) {
                const float4 d4 = *(const float4*)&ds[dd + 2 * j][h];
                s[j] = fmaf(w4.x, d4.x, s[j]);
                s[j] = fmaf(w4.y, d4.y, s[j]);
                s[j] = fmaf(w4.z, d4.z, s[j]);
                s[j] = fmaf(w4.w, d4.w, s[j]);
            }
        }
        const float wb = Wb[k], vw = Vw[k];
        const int g = k >> 2, jj = k & 3;
        #pragma unroll
        for (int j = 0; j < 8; ++j) {
            const int rl = dd + 2 * j;
            const float td = ftanh(s[j] + wb);
            const size_t off = ((size_t)((R0 >> 2) + (rl >> 2)) * 32 + g) * 36;
            g_tdvt[off + 4 + (rl & 3) * 4 + jj] = td;
            g_tdvt[off + 20 + (rl & 3) * 4 + jj] = vw * td;
        }
        if (dd == 0) {
            #pragma unroll
            for (int dl = 0; dl < 4; ++dl)
                g_tdvt[((size_t)((R0 >> 2) + dl) * 32 + g) * 36 + jj] = vw;
        }
    }
}

// 4 h-terms combined into one rcp; 1 SGPR operand max per instruction:
// p = fma(td_s, te_v, 1); x = fma(v4_v, te_v, vt_s)  (v4 hoisted to VGPR per g)
__device__ __forceinline__ float term4(const float4 td, const float4 vt, const float4 v4,
                                       const F4 te, float acc) {
    const float p0 = fmaf(td.x, te.f[0], 1.f);
    const float p1 = fmaf(td.y, te.f[1], 1.f);
    const float p2 = fmaf(td.z, te.f[2], 1.f);
    const float p3 = fmaf(td.w, te.f[3], 1.f);
    const float x0 = fmaf(v4.x, te.f[0], vt.x);
    const float x1 = fmaf(v4.y, te.f[1], vt.y);
    const float x2 = fmaf(v4.z, te.f[2], vt.z);
    const float x3 = fmaf(v4.w, te.f[3], vt.w);
    const float p01 = p0 * p1, p23 = p2 * p3;
    const float u = fmaf(x1, p0, x0 * p1);
    const float zz = fmaf(x3, p2, x2 * p3);
    const float num = fmaf(zz, p01, u * p23);
    return fmaf(num, __builtin_amdgcn_rcpf(p01 * p23), acc);
}

#define DALL(S, TE)                              \
    acc0 = term4(S.td0, S.vt0, S.v4, TE, acc0);  \
    acc1 = term4(S.td1, S.vt1, S.v4, TE, acc1);  \
    acc2 = term4(S.td2, S.vt2, S.v4, TE, acc2);  \
    acc3 = term4(S.td3, S.vt3, S.v4, TE, acc3);

// grid 1024 = (b x 128 row-tiles) x 2 e-halves; block 512 thr; thread owns 1 e.
// No LDS, no barriers; broadcasts via uniform s_loads; 2-deep pipeline.
__global__ __launch_bounds__(512) void score_kernel() {
    const int t = threadIdx.x, blk = blockIdx.x;
    const int rt = blk >> 1, eh = blk & 1;
    const int b = rt >> 7;
    const int R0 = rt * DT;
    const TDVG* tp = (const TDVG*)g_tdvt + (size_t)rt * 32;
    const float* teb = g_tetp + (((size_t)b * 32) * TENC + eh * 512 + t) * 4;

    float acc0 = 0.f, acc1 = 0.f, acc2 = 0.f, acc3 = 0.f;

    TDVG A = tp[0];
    F4 tea; tea.v = *(const float4*)teb;

    for (int g = 0; g < 32; g += 2) {
        F4 teb4; teb4.v = *(const float4*)(teb + (size_t)(g + 1) * 4096);
        TDVG Bv = tp[g + 1];

        DALL(A, tea);

        if (g + 2 < 32) {
            tea.v = *(const float4*)(teb + (size_t)(g + 2) * 4096);
            A = tp[g + 2];
        }

        DALL(Bv, teb4);
    }

    float* so = g_scr + (size_t)R0 * TENC + eh * 512 + t;
    so[0 * TENC] = acc0;
    so[1 * TENC] = acc1;
    so[2 * TENC] = acc2;
    so[3 * TENC] = acc3;
}

// softmax + context: block = (b, row-tile of 4, h-half of 64)
__global__ __launch_bounds__(512, 8) void smctx_kernel(const float* __restrict__ enc,
                                                       float* __restrict__ out) {
    __shared__ float sc[DT][TENC];
    __shared__ float2 part[16][DT][33];
    __shared__ float maxp[2][DT], sump[2][DT];
    const int t = threadIdx.x;
    const int blk = blockIdx.x;
    const int hh = blk & 1, dt = (blk >> 1) & 127, b = blk >> 8;
    const int R0 = b * TDEC + dt * DT;

    {
        const int w = t >> 6, lane = t & 63;
        const int d = w & 3, eh = w >> 2;
        const float* sr = g_scr + (size_t)(R0 + d) * TENC + eh * 512 + lane;
        float v[8];
        float m = -3.0e38f;
        #pragma unroll
        for (int i = 0; i < 8; ++i) { v[i] = sr[i * 64]; m = fmaxf(m, v[i]); }
        #pragma unroll
        for (int off = 32; off; off >>= 1) m = fmaxf(m, __shfl_xor(m, off));
        if (lane == 0) maxp[eh][d] = m;
        __syncthreads();
        m = fmaxf(maxp[0][d], maxp[1][d]);
        float s = 0.f;
        #pragma unroll
        for (int i = 0; i < 8; ++i) {
            const float p = __expf(v[i] - m);
            sc[d][eh * 512 + lane + i * 64] = p;
            s += p;
        }
        #pragma unroll
        for (int off = 32; off; off >>= 1) s += __shfl_xor(s, off);
        if (lane == 0) sump[eh][d] = s;
    }
    __syncthreads();

    {
        const int q = t >> 5, h2 = t & 31;
        const float* eb = enc + (size_t)b * TENC * H_ + hh * 64 + 2 * h2;
        float2 acc[DT];
        #pragma unroll
        for (int d = 0; d < DT; ++d) acc[d] = make_float2(0.f, 0.f);
        for (int e = q * 64; e < q * 64 + 64; e += 4) {
            F4 p4[DT];
            #pragma unroll
            for (int d = 0; d < DT; ++d) p4[d].v = *(const float4*)&sc[d][e];
            #pragma unroll
            for (int j = 0; j < 4; ++j) {
                const float2 ev = *(const float2*)(eb + (size_t)(e + j) * H_);
                #pragma unroll
                for (int d = 0; d < DT; ++d) {
                    acc[d].x = fmaf(p4[d].f[j], ev.x, acc[d].x);
                    acc[d].y = fmaf(p4[d].f[j], ev.y, acc[d].y);
                }
            }
        }
        #pragma unroll
        for (int d = 0; d < DT; ++d) part[q][d][h2] = acc[d];
    }
    __syncthreads();

    if (t < 128) {
        const int d = t >> 5, h2 = t & 31;
        float2 s = make_float2(0.f, 0.f);
        #pragma unroll
        for (int q = 0; q < 16; ++q) {
            const float2 pp = part[q][d][h2];
            s.x += pp.x; s.y += pp.y;
        }
        const float rinv = __builtin_amdgcn_rcpf(sump[0][d] + sump[1][d]);
        s.x *= rinv; s.y *= rinv;
        *(float2*)(out + (size_t)(R0 + d) * H_ + hh * 64 + 2 * h2) = s;
    }
}

extern "C" void kernel_launch(void* const* d_in, const int* in_sizes, int n_in,
                              void* d_out, int out_size, void* d_ws, size_t ws_size,
                              hipStream_t stream) {
    const float* dec = (const float*)d_in[0];
    const float* enc = (const float*)d_in[1];
    const float* Ww  = (const float*)d_in[2];
    const float* Wb  = (const float*)d_in[3];
    const float* Vw  = (const float*)d_in[4];
    float* out = (float*)d_out;

    prep_kernel<<<dim3(TENC / 32, H_ / 32, B_ + 1), dim3(32, 8), 0, stream>>>(
        enc, dec, Ww, Wb, Vw);
    score_kernel<<<dim3(B_ * 128 * 2), dim3(512), 0, stream>>>();
    smctx_kernel<<<dim3(B_ * 128 * 2), dim3(512), 0, stream>>>(enc, out);
}